// Round 5
// baseline (654.962 us; speedup 1.0000x reference)
//
#include <hip/hip_runtime.h>
#include <cstdint>
#include <cmath>

#define DIM   768
#define HID   3072
#define NEXP  8
#define DLOW  192
#define NPB   1024            // tokens per image (32*32)
#define NTOK  8192
#define KD    1536            // NEXP*DLOW
#define KCAT  4608            // HID + KD
#define SPLITS 4

typedef unsigned short ushort_t;
typedef short   short8  __attribute__((ext_vector_type(8)));
typedef float   float4v __attribute__((ext_vector_type(4)));

__device__ inline ushort_t f2b(float f) {
    union { float f; unsigned int i; } v; v.f = f;
    unsigned int x = v.i;
    return (ushort_t)((x + 0x7fffu + ((x >> 16) & 1u)) >> 16);   // RNE
}
__device__ inline float b2f(ushort_t u) {
    union { unsigned int i; float f; } v; v.i = ((unsigned int)u) << 16; return v.f;
}
__device__ inline float gelu_exact(float v) {
    return 0.5f * v * (1.0f + erff(v * 0.70710678118654752440f));
}

// async global->LDS, 16 B per lane (global_load_lds_dwordx4)
__device__ __forceinline__ void async_ld16(const ushort_t* g, ushort_t* l) {
    __builtin_amdgcn_global_load_lds(
        (const __attribute__((address_space(1))) void*)g,
        (__attribute__((address_space(3))) void*)l,
        16, 0, 0);
}

// ---------------------------------------------------------------------------
// GEMM: acc[m,n] = sum_k A[m,k]*B[n,k]  (bf16, k-contiguous rows, row stride=K)
// 128x128 tile, BK=64, XOR-swizzled LDS, async staging, 4 waves.
// MODE 0: Cb[m*ldc+col] = bf16(acc)
// MODE 1: Cb[m*ldc+col] = bf16(gelu(acc + bias[col]))
// MODE 4: atomicAdd(Cf[(b*DIM+col)*NPB+nn], acc)  split-K over blockIdx.z
// ---------------------------------------------------------------------------
template<int MODE>
__global__ __launch_bounds__(256)
void gemm_bt(const ushort_t* __restrict__ A, const ushort_t* __restrict__ B,
             ushort_t* __restrict__ Cb, float* __restrict__ Cf,
             const float* __restrict__ bias,
             int N, int K, int ldc, int m_base, int kslice)
{
    __shared__ __align__(16) ushort_t As[128 * 64];
    __shared__ __align__(16) ushort_t Bs[128 * 64];

    const int tid  = threadIdx.x;
    const int lane = tid & 63;
    const int wave = tid >> 6;
    const int quad = lane >> 4;
    const int l16  = lane & 15;
    const int wm   = (wave >> 1) * 64;
    const int wn   = (wave & 1) * 64;
    const int m0   = blockIdx.y * 128;
    const int n0   = blockIdx.x * 128;

    float4v acc[4][4];
#pragma unroll
    for (int i = 0; i < 4; i++)
#pragma unroll
        for (int j = 0; j < 4; j++) acc[i][j] = (float4v)0.0f;

    // staging: LDS slot f holds global k-group (f&7)^(m&7) of row m=f>>3
    const ushort_t* ga[4]; const ushort_t* gb[4];
    ushort_t* la[4]; ushort_t* lb[4];
#pragma unroll
    for (int j = 0; j < 4; j++) {
        const int f = j * 256 + tid;
        const int m = f >> 3;
        const int gs = ((f & 7) ^ (m & 7)) * 8;
        ga[j] = A + (size_t)(m0 + m) * K + gs;
        gb[j] = B + (size_t)(n0 + m) * K + gs;
        la[j] = &As[f * 8];
        lb[j] = &Bs[f * 8];
    }

    // fragment LDS pointers (loop-invariant): group (quad+4*kh) of row r at
    // slot (quad+4*kh)^(r&7)
    const ushort_t* pa[2][4]; const ushort_t* pb[2][4];
#pragma unroll
    for (int kh = 0; kh < 2; kh++)
#pragma unroll
        for (int i = 0; i < 4; i++) {
            const int ra = wm + i * 16 + l16;
            pa[kh][i] = &As[ra * 64 + (((quad + 4 * kh) ^ (ra & 7)) * 8)];
            const int rb = wn + i * 16 + l16;
            pb[kh][i] = &Bs[rb * 64 + (((quad + 4 * kh) ^ (rb & 7)) * 8)];
        }

    int kb = 0, ke = K;
    if (MODE == 4) { kb = blockIdx.z * kslice; ke = kb + kslice; }

    for (int k0 = kb; k0 < ke; k0 += 64) {
        __syncthreads();                  // prior iter's ds_reads complete
#pragma unroll
        for (int j = 0; j < 4; j++) async_ld16(ga[j] + k0, la[j]);
#pragma unroll
        for (int j = 0; j < 4; j++) async_ld16(gb[j] + k0, lb[j]);
        __syncthreads();                  // staged data visible

#pragma unroll
        for (int kh = 0; kh < 2; kh++) {
            short8 af[4], bv[4];
#pragma unroll
            for (int i = 0; i < 4; i++) af[i] = *(const short8*)pa[kh][i];
#pragma unroll
            for (int i = 0; i < 4; i++) bv[i] = *(const short8*)pb[kh][i];
#pragma unroll
            for (int im = 0; im < 4; im++)
#pragma unroll
                for (int in = 0; in < 4; in++)
                    acc[im][in] = __builtin_amdgcn_mfma_f32_16x16x32_bf16(
                        af[im], bv[in], acc[im][in], 0, 0, 0);
        }
    }

#pragma unroll
    for (int in = 0; in < 4; in++) {
        const int col = n0 + wn + in * 16 + l16;
        const float bvv = (MODE == 1) ? bias[col] : 0.0f;
#pragma unroll
        for (int im = 0; im < 4; im++) {
            const int rowl = m0 + wm + im * 16 + quad * 4;
            if (MODE <= 1) {
#pragma unroll
                for (int r = 0; r < 4; r++) {
                    float v = acc[im][in][r] + bvv;
                    if (MODE == 1) v = gelu_exact(v);
                    Cb[(size_t)(rowl + r) * ldc + col] = f2b(v);
                }
            } else {                      // MODE 4
                const int grow = m_base + rowl;
                const int bb = grow >> 10, nn = grow & 1023;
                const size_t base = ((size_t)bb * DIM + col) * NPB + nn;
#pragma unroll
                for (int r = 0; r < 4; r++)
                    atomicAdd(&Cf[base + r], acc[im][in][r]);
            }
        }
    }
}

// ---------------------------------------------------------------------------
// x f32 [B,C,N] -> XTbf bf16 [T,C]
// ---------------------------------------------------------------------------
__global__ void transpose_x_cvt(const float* __restrict__ x, ushort_t* __restrict__ XT)
{
    __shared__ ushort_t tile[32][33];
    const int tx = threadIdx.x, ty = threadIdx.y;
    const int n0 = blockIdx.x * 32, c0 = blockIdx.y * 32, b = blockIdx.z;
#pragma unroll
    for (int j = 0; j < 4; j++)
        tile[ty + 8 * j][tx] = f2b(x[((size_t)b * DIM + c0 + ty + 8 * j) * NPB + n0 + tx]);
    __syncthreads();
#pragma unroll
    for (int j = 0; j < 4; j++)
        XT[((size_t)b * NPB + n0 + ty + 8 * j) * DIM + c0 + tx] = tile[tx][ty + 8 * j];
}

// w_up f32 [KD][DIM] -> Wcat[:, HID:KCAT] bf16 (row stride KCAT)
__global__ void transpose_wup_cat(const float* __restrict__ src, ushort_t* __restrict__ Wcat)
{
    __shared__ ushort_t tile[32][33];
    const int tx = threadIdx.x, ty = threadIdx.y;
    const int c0 = blockIdx.x * 32, k0 = blockIdx.y * 32;
#pragma unroll
    for (int j = 0; j < 4; j++)
        tile[ty + 8 * j][tx] = f2b(src[(size_t)(k0 + ty + 8 * j) * DIM + c0 + tx]);
    __syncthreads();
#pragma unroll
    for (int j = 0; j < 4; j++)
        Wcat[(size_t)(c0 + ty + 8 * j) * KCAT + HID + k0 + tx] = tile[tx][ty + 8 * j];
}

// w2 f32 [DIM][HID] -> Wcat[:, 0:HID] bf16 (row stride KCAT)
__global__ void cvt_w2_cat(const float* __restrict__ w2, ushort_t* __restrict__ Wcat)
{
    const int i = blockIdx.x * 256 + threadIdx.x;    // < DIM*HID/4
    const int c = i / (HID / 4), h = (i % (HID / 4)) * 4;
    const float4 v = *(const float4*)(w2 + (size_t)c * HID + h);
    uint2 p;
    p.x = (unsigned)f2b(v.x) | ((unsigned)f2b(v.y) << 16);
    p.y = (unsigned)f2b(v.z) | ((unsigned)f2b(v.w) << 16);
    *(uint2*)(Wcat + (size_t)c * KCAT + h) = p;
}

// f32 -> bf16 elementwise (count4 = elems/4), packed stores
__global__ void cvt_bf16(const float* __restrict__ src, ushort_t* __restrict__ dst, int count4)
{
    const int i = blockIdx.x * 256 + threadIdx.x;
    if (i >= count4) return;
    const float4 v = *(const float4*)(src + (size_t)i * 4);
    uint2 p;
    p.x = (unsigned)f2b(v.x) | ((unsigned)f2b(v.y) << 16);
    p.y = (unsigned)f2b(v.z) | ((unsigned)f2b(v.w) << 16);
    *(uint2*)(dst + (size_t)i * 4) = p;
}

// out[b,c,n] = x[b,c,n] + b2[c]   (pre-init for split-K atomics)
__global__ void init_out(const float* __restrict__ x, const float* __restrict__ b2,
                         float* __restrict__ out)
{
    const int i = blockIdx.x * 256 + threadIdx.x;    // over B*DIM*NPB/4
    const int n4 = (i & 255) * 4, bc = i >> 8;
    const int c = bc % DIM;
    const size_t o = (size_t)bc * NPB + n4;
    float4 v = *(const float4*)(x + o);
    const float bb = b2[c];
    v.x += bb; v.y += bb; v.z += bb; v.w += bb;
    *(float4*)(out + o) = v;
}

// ---------------------------------------------------------------------------
// Weff[e][c] = sum_d w_down[e*192+d][c] * rw[d]   (all f32, exact fold)
// ---------------------------------------------------------------------------
__global__ __launch_bounds__(256)
void weff_kernel(const float* __restrict__ wdn, const float* __restrict__ rw,
                 float* __restrict__ Weff)
{
    const int idx = blockIdx.x * 256 + threadIdx.x;   // 0..6143
    const int e = idx / DIM, c = idx % DIM;
    float s = 0.0f;
    for (int d = 0; d < DLOW; d++)
        s += wdn[(size_t)(e * DLOW + d) * DIM + c] * rw[d];
    Weff[idx] = s;
}

// ---------------------------------------------------------------------------
// Router (all f32): thread t owns one token. logits -> softmax -> top2 -> aux
// ---------------------------------------------------------------------------
__global__ __launch_bounds__(256)
void router_kernel(const float* __restrict__ x, const float* __restrict__ Weff,
                   int* __restrict__ tokE, float* __restrict__ tokW,
                   float* __restrict__ accbuf)
{
    __shared__ float sW[NEXP * DIM];
    __shared__ float sAcc[16];
    const int tid = threadIdx.x;
    for (int i = tid; i < NEXP * DIM; i += 256) sW[i] = Weff[i];
    if (tid < 16) sAcc[tid] = 0.0f;
    __syncthreads();

    const int t = blockIdx.x * 256 + tid;
    const int b = t >> 10, n = t & 1023;
    const float* xb = x + (size_t)b * DIM * NPB + n;

    float lg[8];
#pragma unroll
    for (int e = 0; e < 8; e++) lg[e] = 0.0f;
    for (int c = 0; c < DIM; c++) {
        const float xv = xb[(size_t)c * NPB];
#pragma unroll
        for (int e = 0; e < 8; e++) lg[e] += xv * sW[e * DIM + c];
    }

    float mx = lg[0];
#pragma unroll
    for (int e = 1; e < 8; e++) mx = fmaxf(mx, lg[e]);
    float pr[8], s = 0.0f;
#pragma unroll
    for (int e = 0; e < 8; e++) { pr[e] = expf(lg[e] - mx); s += pr[e]; }
    const float inv = 1.0f / s;
#pragma unroll
    for (int e = 0; e < 8; e++) pr[e] *= inv;
    int e0 = 0;
#pragma unroll
    for (int e = 1; e < 8; e++) if (pr[e] > pr[e0]) e0 = e;
    int e1 = (e0 == 0) ? 1 : 0;
#pragma unroll
    for (int e = 0; e < 8; e++) if (e != e0 && pr[e] > pr[e1]) e1 = e;
    const float wsum = pr[e0] + pr[e1];
    tokE[2 * t + 0] = e0;  tokE[2 * t + 1] = e1;
    tokW[2 * t + 0] = pr[e0] / wsum;  tokW[2 * t + 1] = pr[e1] / wsum;

#pragma unroll
    for (int e = 0; e < 8; e++) atomicAdd(&sAcc[e], pr[e]);
    atomicAdd(&sAcc[8 + e0], 1.0f);
    atomicAdd(&sAcc[8 + e1], 1.0f);
    __syncthreads();
    if (tid < 16) atomicAdd(&accbuf[tid], sAcc[tid]);
}

// ---------------------------------------------------------------------------
// Densify in-place on strided feats (row stride KCAT); optionally write aux
// ---------------------------------------------------------------------------
__global__ __launch_bounds__(256)
void actw_kernel(ushort_t* __restrict__ FB, int t0, const int* __restrict__ tokE,
                 const float* __restrict__ tokW, const float* __restrict__ accbuf,
                 float* __restrict__ outAux)
{
    const int tl = blockIdx.x;
    const int t = t0 + tl;
    const int e0 = tokE[2 * t], e1 = tokE[2 * t + 1];
    const float w0 = tokW[2 * t], w1 = tokW[2 * t + 1];
    ushort_t* row = FB + (size_t)tl * KCAT;
#pragma unroll
    for (int j = 0; j < 6; j++) {
        const int k = j * 256 + threadIdx.x;
        const int e = k / DLOW;
        const float f = b2f(row[k]);
        const float m = (e == e0) ? w0 : ((e == e1) ? w1 : 0.0f);
        row[k] = f2b(gelu_exact(f) * m);
    }
    if (outAux != nullptr && blockIdx.x == 0 && threadIdx.x == 0) {
        float aux = 0.0f;
        for (int e = 0; e < 8; e++) aux += accbuf[e] * accbuf[8 + e];
        outAux[0] = aux * 8.0f / ((float)NTOK * (float)NTOK);
    }
}

// ---------------------------------------------------------------------------
extern "C" void kernel_launch(void* const* d_in, const int* in_sizes, int n_in,
                              void* d_out, int out_size, void* d_ws, size_t ws_size,
                              hipStream_t stream)
{
    (void)in_sizes; (void)n_in; (void)out_size;

    const float* x   = (const float*)d_in[0];
    const float* w1  = (const float*)d_in[1];
    const float* b1  = (const float*)d_in[2];
    const float* w2  = (const float*)d_in[3];
    const float* b2  = (const float*)d_in[4];
    const float* wdn = (const float*)d_in[5];
    const float* rw  = (const float*)d_in[6];
    const float* wup = (const float*)d_in[7];
    float* out = (float*)d_out;

    char* ws = (char*)d_ws;
    size_t off = 0;
    ushort_t* XTbf = (ushort_t*)(ws + off); off += (size_t)NTOK * DIM * 2;   // 12.6 MB
    ushort_t* w1b  = (ushort_t*)(ws + off); off += (size_t)HID * DIM * 2;    //  4.7 MB
    ushort_t* wdnb = (ushort_t*)(ws + off); off += (size_t)KD * DIM * 2;     //  2.4 MB
    ushort_t* Wcat = (ushort_t*)(ws + off); off += (size_t)DIM * KCAT * 2;   //  7.1 MB
    float*    Weff = (float*)  (ws + off);  off += (size_t)NEXP * DIM * 4;
    int*      tokE = (int*)    (ws + off);  off += (size_t)NTOK * 2 * 4;
    float*    tokW = (float*)  (ws + off);  off += (size_t)NTOK * 2 * 4;
    float*    accb = (float*)  (ws + off);  off += 256;
    ushort_t* HU   = (ushort_t*)(ws + off); // chunk*KCAT bf16  [hidden | feats]

    // largest token-chunk that fits (graph-safe: pure function of ws_size)
    int chunk = NTOK / 4;
    if (ws_size >= off + (size_t)NTOK * KCAT * 2)          chunk = NTOK;
    else if (ws_size >= off + (size_t)(NTOK / 2) * KCAT * 2) chunk = NTOK / 2;

    const dim3 tb(32, 8);
    transpose_x_cvt  <<<dim3(32, 24, 8), tb, 0, stream>>>(x, XTbf);
    transpose_wup_cat<<<dim3(24, 48),    tb, 0, stream>>>(wup, Wcat);
    cvt_w2_cat<<<DIM * HID / 4 / 256, 256, 0, stream>>>(w2, Wcat);
    cvt_bf16<<<(HID * DIM / 4 + 255) / 256, 256, 0, stream>>>(w1, w1b, HID * DIM / 4);
    cvt_bf16<<<(KD * DIM / 4 + 255) / 256, 256, 0, stream>>>(wdn, wdnb, KD * DIM / 4);
    weff_kernel<<<NEXP * DIM / 256, 256, 0, stream>>>(wdn, rw, Weff);

    hipMemsetAsync(accb, 0, 64, stream);
    router_kernel<<<NTOK / 256, 256, 0, stream>>>(x, Weff, tokE, tokW, accb);
    init_out<<<8 * DIM * NPB / 4 / 256, 256, 0, stream>>>(x, b2, out);

    for (int c = 0; c < NTOK / chunk; c++) {
        const ushort_t* Ax = XTbf + (size_t)c * chunk * DIM;
        // HU[:, 0:HID] = gelu(XT @ w1^T + b1)
        gemm_bt<1><<<dim3(HID / 128, chunk / 128), 256, 0, stream>>>(
            Ax, w1b, HU, nullptr, b1, HID, DIM, KCAT, 0, 0);
        // HU[:, HID:KCAT] = XT @ w_down^T
        gemm_bt<0><<<dim3(KD / 128, chunk / 128), 256, 0, stream>>>(
            Ax, wdnb, HU + HID, nullptr, nullptr, KD, DIM, KCAT, 0, 0);
        // densify feats in place (+aux once)
        actw_kernel<<<chunk, 256, 0, stream>>>(
            HU + HID, c * chunk, tokE, tokW, accb,
            (c == 0) ? out + (size_t)NTOK * DIM : nullptr);
        // out += HU @ Wcat^T   (split-K atomics)
        gemm_bt<4><<<dim3(DIM / 128, chunk / 128, SPLITS), 256, 0, stream>>>(
            HU, Wcat, nullptr, out, nullptr, DIM, KCAT, 0, c * chunk, KCAT / SPLITS);
    }
}

// Round 6
// 383.859 us; speedup vs baseline: 1.7063x; 1.7063x over previous
//
#include <hip/hip_runtime.h>
#include <cstdint>
#include <cmath>

#define DIM   768
#define HID   3072
#define NEXP  8
#define DLOW  192
#define NPB   1024            // tokens per image (32*32)
#define NTOK  8192
#define KD    1536            // NEXP*DLOW
#define KCAT  4608            // HID + KD

typedef unsigned short ushort_t;
typedef short   short8  __attribute__((ext_vector_type(8)));
typedef float   float4v __attribute__((ext_vector_type(4)));

__device__ inline ushort_t f2b(float f) {
    union { float f; unsigned int i; } v; v.f = f;
    unsigned int x = v.i;
    return (ushort_t)((x + 0x7fffu + ((x >> 16) & 1u)) >> 16);   // RNE
}
__device__ inline float b2f(ushort_t u) {
    union { unsigned int i; float f; } v; v.i = ((unsigned int)u) << 16; return v.f;
}
__device__ inline float gelu_exact(float v) {
    return 0.5f * v * (1.0f + erff(v * 0.70710678118654752440f));
}

// async global->LDS, 16 B per lane (global_load_lds_dwordx4)
__device__ __forceinline__ void async_ld16(const ushort_t* g, ushort_t* l) {
    __builtin_amdgcn_global_load_lds(
        (const __attribute__((address_space(1))) void*)g,
        (__attribute__((address_space(3))) void*)l,
        16, 0, 0);
}

// ---------------------------------------------------------------------------
// INPUT GEMM (r4-proven BK=32 core): HU[m, col] over col in [0, KCAT)
//   acc = XT[m,:] . Win[col,:]  (K=768)
//   col <  HID : HU = bf16(gelu(acc + b1[col]))
//   col >= HID : HU = bf16(acc)
// ---------------------------------------------------------------------------
__global__ __launch_bounds__(256)
void gemm_in(const ushort_t* __restrict__ A, const ushort_t* __restrict__ B,
             ushort_t* __restrict__ Cb, const float* __restrict__ bias)
{
    const int K = DIM;
    __shared__ __align__(16) ushort_t As[128 * 32];
    __shared__ __align__(16) ushort_t Bs[128 * 32];

    const int tid  = threadIdx.x;
    const int lane = tid & 63;
    const int wave = tid >> 6;
    const int quad = lane >> 4;
    const int l16  = lane & 15;
    const int wm   = (wave >> 1) * 64;
    const int wn   = (wave & 1) * 64;
    const int m0   = blockIdx.y * 128;
    const int n0   = blockIdx.x * 128;

    float4v acc[4][4];
#pragma unroll
    for (int i = 0; i < 4; i++)
#pragma unroll
        for (int j = 0; j < 4; j++) acc[i][j] = (float4v)0.0f;

    const int f0 = tid, f1 = 256 + tid;
    const ushort_t* ga0 = A + (size_t)(m0 + (f0 >> 2)) * K + (f0 & 3) * 8;
    const ushort_t* ga1 = A + (size_t)(m0 + (f1 >> 2)) * K + (f1 & 3) * 8;
    const ushort_t* gb0 = B + (size_t)(n0 + (f0 >> 2)) * K + (f0 & 3) * 8;
    const ushort_t* gb1 = B + (size_t)(n0 + (f1 >> 2)) * K + (f1 & 3) * 8;
    ushort_t* la0 = &As[f0 * 8];
    ushort_t* la1 = &As[f1 * 8];
    ushort_t* lb0 = &Bs[f0 * 8];
    ushort_t* lb1 = &Bs[f1 * 8];

    for (int k0 = 0; k0 < K; k0 += 32) {
        __syncthreads();
        async_ld16(ga0 + k0, la0);
        async_ld16(ga1 + k0, la1);
        async_ld16(gb0 + k0, lb0);
        async_ld16(gb1 + k0, lb1);
        __syncthreads();

        short8 af[4], bv[4];
#pragma unroll
        for (int im = 0; im < 4; im++)
            af[im] = *(const short8*)&As[(wm + im * 16 + l16) * 32 + quad * 8];
#pragma unroll
        for (int in = 0; in < 4; in++)
            bv[in] = *(const short8*)&Bs[(wn + in * 16 + l16) * 32 + quad * 8];
#pragma unroll
        for (int im = 0; im < 4; im++)
#pragma unroll
            for (int in = 0; in < 4; in++)
                acc[im][in] = __builtin_amdgcn_mfma_f32_16x16x32_bf16(
                    af[im], bv[in], acc[im][in], 0, 0, 0);
    }

    const bool doGelu = (n0 < HID);       // HID % 128 == 0: block-uniform
#pragma unroll
    for (int in = 0; in < 4; in++) {
        const int col = n0 + wn + in * 16 + l16;
        const float bvv = doGelu ? bias[col] : 0.0f;
#pragma unroll
        for (int im = 0; im < 4; im++) {
            const int rowl = m0 + wm + im * 16 + quad * 4;
#pragma unroll
            for (int r = 0; r < 4; r++) {
                float v = acc[im][in][r] + bvv;
                if (doGelu) v = gelu_exact(v);
                Cb[(size_t)(rowl + r) * KCAT + col] = f2b(v);
            }
        }
    }
}

// ---------------------------------------------------------------------------
// OUTPUT GEMM (r5 swizzled BK=64 core, direct epilogue, no atomics):
//   acc = HU[m,:] . Wcat[col,:]  (K=4608)
//   out[b, col, nn] = acc + b2[col] + x[b, col, nn],  token m_base+m
// ---------------------------------------------------------------------------
__global__ __launch_bounds__(256)
void gemm_out(const ushort_t* __restrict__ A, const ushort_t* __restrict__ B,
              float* __restrict__ out, const float* __restrict__ bias,
              const float* __restrict__ X, int m_base)
{
    const int K = KCAT;
    __shared__ __align__(16) ushort_t As[128 * 64];
    __shared__ __align__(16) ushort_t Bs[128 * 64];

    const int tid  = threadIdx.x;
    const int lane = tid & 63;
    const int wave = tid >> 6;
    const int quad = lane >> 4;
    const int l16  = lane & 15;
    const int wm   = (wave >> 1) * 64;
    const int wn   = (wave & 1) * 64;
    const int m0   = blockIdx.y * 128;
    const int n0   = blockIdx.x * 128;

    float4v acc[4][4];
#pragma unroll
    for (int i = 0; i < 4; i++)
#pragma unroll
        for (int j = 0; j < 4; j++) acc[i][j] = (float4v)0.0f;

    // staging: LDS slot f holds global k-group (f&7)^(m&7) of row m=f>>3
    const ushort_t* ga[4]; const ushort_t* gb[4];
    ushort_t* la[4]; ushort_t* lb[4];
#pragma unroll
    for (int j = 0; j < 4; j++) {
        const int f = j * 256 + tid;
        const int m = f >> 3;
        const int gs = ((f & 7) ^ (m & 7)) * 8;
        ga[j] = A + (size_t)(m0 + m) * K + gs;
        gb[j] = B + (size_t)(n0 + m) * K + gs;
        la[j] = &As[f * 8];
        lb[j] = &Bs[f * 8];
    }

    // fragment LDS pointers (loop-invariant, swizzle-resolved)
    const ushort_t* pa[2][4]; const ushort_t* pb[2][4];
#pragma unroll
    for (int kh = 0; kh < 2; kh++)
#pragma unroll
        for (int i = 0; i < 4; i++) {
            const int ra = wm + i * 16 + l16;
            pa[kh][i] = &As[ra * 64 + (((quad + 4 * kh) ^ (ra & 7)) * 8)];
            const int rb = wn + i * 16 + l16;
            pb[kh][i] = &Bs[rb * 64 + (((quad + 4 * kh) ^ (rb & 7)) * 8)];
        }

    for (int k0 = 0; k0 < K; k0 += 64) {
        __syncthreads();
#pragma unroll
        for (int j = 0; j < 4; j++) async_ld16(ga[j] + k0, la[j]);
#pragma unroll
        for (int j = 0; j < 4; j++) async_ld16(gb[j] + k0, lb[j]);
        __syncthreads();

#pragma unroll
        for (int kh = 0; kh < 2; kh++) {
            short8 af[4], bv[4];
#pragma unroll
            for (int i = 0; i < 4; i++) af[i] = *(const short8*)pa[kh][i];
#pragma unroll
            for (int i = 0; i < 4; i++) bv[i] = *(const short8*)pb[kh][i];
#pragma unroll
            for (int im = 0; im < 4; im++)
#pragma unroll
                for (int in = 0; in < 4; in++)
                    acc[im][in] = __builtin_amdgcn_mfma_f32_16x16x32_bf16(
                        af[im], bv[in], acc[im][in], 0, 0, 0);
        }
    }

#pragma unroll
    for (int in = 0; in < 4; in++) {
        const int col = n0 + wn + in * 16 + l16;
        const float bvv = bias[col];
#pragma unroll
        for (int im = 0; im < 4; im++) {
            const int grow = m_base + m0 + wm + im * 16 + quad * 4;
            const int bb = grow >> 10, nn = grow & 1023;
            const size_t base = ((size_t)bb * DIM + col) * NPB + nn;
            const float4 xv = *(const float4*)(X + base);
            float4 v;
            v.x = acc[im][in][0] + bvv + xv.x;
            v.y = acc[im][in][1] + bvv + xv.y;
            v.z = acc[im][in][2] + bvv + xv.z;
            v.w = acc[im][in][3] + bvv + xv.w;
            *(float4*)(out + base) = v;
        }
    }
}

// ---------------------------------------------------------------------------
// x f32 [B,C,N] -> XTbf bf16 [T,C]
// ---------------------------------------------------------------------------
__global__ void transpose_x_cvt(const float* __restrict__ x, ushort_t* __restrict__ XT)
{
    __shared__ ushort_t tile[32][33];
    const int tx = threadIdx.x, ty = threadIdx.y;
    const int n0 = blockIdx.x * 32, c0 = blockIdx.y * 32, b = blockIdx.z;
#pragma unroll
    for (int j = 0; j < 4; j++)
        tile[ty + 8 * j][tx] = f2b(x[((size_t)b * DIM + c0 + ty + 8 * j) * NPB + n0 + tx]);
    __syncthreads();
#pragma unroll
    for (int j = 0; j < 4; j++)
        XT[((size_t)b * NPB + n0 + ty + 8 * j) * DIM + c0 + tx] = tile[tx][ty + 8 * j];
}

// w_up f32 [KD][DIM] -> Wcat[:, HID:KCAT] bf16 (row stride KCAT)
__global__ void transpose_wup_cat(const float* __restrict__ src, ushort_t* __restrict__ Wcat)
{
    __shared__ ushort_t tile[32][33];
    const int tx = threadIdx.x, ty = threadIdx.y;
    const int c0 = blockIdx.x * 32, k0 = blockIdx.y * 32;
#pragma unroll
    for (int j = 0; j < 4; j++)
        tile[ty + 8 * j][tx] = f2b(src[(size_t)(k0 + ty + 8 * j) * DIM + c0 + tx]);
    __syncthreads();
#pragma unroll
    for (int j = 0; j < 4; j++)
        Wcat[(size_t)(c0 + ty + 8 * j) * KCAT + HID + k0 + tx] = tile[tx][ty + 8 * j];
}

// w2 f32 [DIM][HID] -> Wcat[:, 0:HID] bf16 (row stride KCAT)
__global__ void cvt_w2_cat(const float* __restrict__ w2, ushort_t* __restrict__ Wcat)
{
    const int i = blockIdx.x * 256 + threadIdx.x;    // < DIM*HID/4
    const int c = i / (HID / 4), h = (i % (HID / 4)) * 4;
    const float4 v = *(const float4*)(w2 + (size_t)c * HID + h);
    uint2 p;
    p.x = (unsigned)f2b(v.x) | ((unsigned)f2b(v.y) << 16);
    p.y = (unsigned)f2b(v.z) | ((unsigned)f2b(v.w) << 16);
    *(uint2*)(Wcat + (size_t)c * KCAT + h) = p;
}

// f32 -> bf16 elementwise (count4 = elems/4), packed stores
__global__ void cvt_bf16(const float* __restrict__ src, ushort_t* __restrict__ dst, int count4)
{
    const int i = blockIdx.x * 256 + threadIdx.x;
    if (i >= count4) return;
    const float4 v = *(const float4*)(src + (size_t)i * 4);
    uint2 p;
    p.x = (unsigned)f2b(v.x) | ((unsigned)f2b(v.y) << 16);
    p.y = (unsigned)f2b(v.z) | ((unsigned)f2b(v.w) << 16);
    *(uint2*)(dst + (size_t)i * 4) = p;
}

// ---------------------------------------------------------------------------
// Weff[e][c] = sum_d w_down[e*192+d][c] * rw[d]   (all f32, exact fold)
// ---------------------------------------------------------------------------
__global__ __launch_bounds__(256)
void weff_kernel(const float* __restrict__ wdn, const float* __restrict__ rw,
                 float* __restrict__ Weff)
{
    const int idx = blockIdx.x * 256 + threadIdx.x;   // 0..6143
    const int e = idx / DIM, c = idx % DIM;
    float s = 0.0f;
    for (int d = 0; d < DLOW; d++)
        s += wdn[(size_t)(e * DLOW + d) * DIM + c] * rw[d];
    Weff[idx] = s;
}

// ---------------------------------------------------------------------------
// Router (all f32): thread t owns one token. logits -> softmax -> top2 -> aux
// ---------------------------------------------------------------------------
__global__ __launch_bounds__(256)
void router_kernel(const float* __restrict__ x, const float* __restrict__ Weff,
                   int* __restrict__ tokE, float* __restrict__ tokW,
                   float* __restrict__ accbuf)
{
    __shared__ float sW[NEXP * DIM];
    __shared__ float sAcc[16];
    const int tid = threadIdx.x;
    for (int i = tid; i < NEXP * DIM; i += 256) sW[i] = Weff[i];
    if (tid < 16) sAcc[tid] = 0.0f;
    __syncthreads();

    const int t = blockIdx.x * 256 + tid;
    const int b = t >> 10, n = t & 1023;
    const float* xb = x + (size_t)b * DIM * NPB + n;

    float lg[8];
#pragma unroll
    for (int e = 0; e < 8; e++) lg[e] = 0.0f;
    for (int c = 0; c < DIM; c++) {
        const float xv = xb[(size_t)c * NPB];
#pragma unroll
        for (int e = 0; e < 8; e++) lg[e] += xv * sW[e * DIM + c];
    }

    float mx = lg[0];
#pragma unroll
    for (int e = 1; e < 8; e++) mx = fmaxf(mx, lg[e]);
    float pr[8], s = 0.0f;
#pragma unroll
    for (int e = 0; e < 8; e++) { pr[e] = expf(lg[e] - mx); s += pr[e]; }
    const float inv = 1.0f / s;
#pragma unroll
    for (int e = 0; e < 8; e++) pr[e] *= inv;
    int e0 = 0;
#pragma unroll
    for (int e = 1; e < 8; e++) if (pr[e] > pr[e0]) e0 = e;
    int e1 = (e0 == 0) ? 1 : 0;
#pragma unroll
    for (int e = 0; e < 8; e++) if (e != e0 && pr[e] > pr[e1]) e1 = e;
    const float wsum = pr[e0] + pr[e1];
    tokE[2 * t + 0] = e0;  tokE[2 * t + 1] = e1;
    tokW[2 * t + 0] = pr[e0] / wsum;  tokW[2 * t + 1] = pr[e1] / wsum;

#pragma unroll
    for (int e = 0; e < 8; e++) atomicAdd(&sAcc[e], pr[e]);
    atomicAdd(&sAcc[8 + e0], 1.0f);
    atomicAdd(&sAcc[8 + e1], 1.0f);
    __syncthreads();
    if (tid < 16) atomicAdd(&accbuf[tid], sAcc[tid]);
}

// ---------------------------------------------------------------------------
// Densify in-place on strided feats (row stride KCAT); optionally write aux
// ---------------------------------------------------------------------------
__global__ __launch_bounds__(256)
void actw_kernel(ushort_t* __restrict__ FB, int t0, const int* __restrict__ tokE,
                 const float* __restrict__ tokW, const float* __restrict__ accbuf,
                 float* __restrict__ outAux)
{
    const int tl = blockIdx.x;
    const int t = t0 + tl;
    const int e0 = tokE[2 * t], e1 = tokE[2 * t + 1];
    const float w0 = tokW[2 * t], w1 = tokW[2 * t + 1];
    ushort_t* row = FB + (size_t)tl * KCAT;
#pragma unroll
    for (int j = 0; j < 6; j++) {
        const int k = j * 256 + threadIdx.x;
        const int e = k / DLOW;
        const float f = b2f(row[k]);
        const float m = (e == e0) ? w0 : ((e == e1) ? w1 : 0.0f);
        row[k] = f2b(gelu_exact(f) * m);
    }
    if (outAux != nullptr && blockIdx.x == 0 && threadIdx.x == 0) {
        float aux = 0.0f;
        for (int e = 0; e < 8; e++) aux += accbuf[e] * accbuf[8 + e];
        outAux[0] = aux * 8.0f / ((float)NTOK * (float)NTOK);
    }
}

// ---------------------------------------------------------------------------
extern "C" void kernel_launch(void* const* d_in, const int* in_sizes, int n_in,
                              void* d_out, int out_size, void* d_ws, size_t ws_size,
                              hipStream_t stream)
{
    (void)in_sizes; (void)n_in; (void)out_size;

    const float* x   = (const float*)d_in[0];
    const float* w1  = (const float*)d_in[1];
    const float* b1  = (const float*)d_in[2];
    const float* w2  = (const float*)d_in[3];
    const float* b2  = (const float*)d_in[4];
    const float* wdn = (const float*)d_in[5];
    const float* rw  = (const float*)d_in[6];
    const float* wup = (const float*)d_in[7];
    float* out = (float*)d_out;

    char* ws = (char*)d_ws;
    size_t off = 0;
    ushort_t* XTbf = (ushort_t*)(ws + off); off += (size_t)NTOK * DIM * 2;   // 12.6 MB
    ushort_t* Win  = (ushort_t*)(ws + off); off += (size_t)KCAT * DIM * 2;   //  7.1 MB  [w1; wdn]
    ushort_t* Wcat = (ushort_t*)(ws + off); off += (size_t)DIM * KCAT * 2;   //  7.1 MB  [w2 | wup^T]
    float*    Weff = (float*)  (ws + off);  off += (size_t)NEXP * DIM * 4;
    int*      tokE = (int*)    (ws + off);  off += (size_t)NTOK * 2 * 4;
    float*    tokW = (float*)  (ws + off);  off += (size_t)NTOK * 2 * 4;
    float*    accb = (float*)  (ws + off);  off += 256;
    ushort_t* HU   = (ushort_t*)(ws + off); // chunk*KCAT bf16  [hidden | feats]

    // largest token-chunk that fits (graph-safe: pure function of ws_size)
    int chunk = NTOK / 4;
    if (ws_size >= off + (size_t)NTOK * KCAT * 2)            chunk = NTOK;
    else if (ws_size >= off + (size_t)(NTOK / 2) * KCAT * 2) chunk = NTOK / 2;

    const dim3 tb(32, 8);
    transpose_x_cvt  <<<dim3(32, 24, 8), tb, 0, stream>>>(x, XTbf);
    transpose_wup_cat<<<dim3(24, 48),    tb, 0, stream>>>(wup, Wcat);
    cvt_w2_cat<<<DIM * HID / 4 / 256, 256, 0, stream>>>(w2, Wcat);
    cvt_bf16<<<(HID * DIM / 4 + 255) / 256, 256, 0, stream>>>(w1, Win, HID * DIM / 4);
    cvt_bf16<<<(KD * DIM / 4 + 255) / 256, 256, 0, stream>>>(wdn, Win + (size_t)HID * DIM, KD * DIM / 4);
    weff_kernel<<<NEXP * DIM / 256, 256, 0, stream>>>(wdn, rw, Weff);

    hipMemsetAsync(accb, 0, 64, stream);
    router_kernel<<<NTOK / 256, 256, 0, stream>>>(x, Weff, tokE, tokW, accb);

    for (int c = 0; c < NTOK / chunk; c++) {
        const ushort_t* Ax = XTbf + (size_t)c * chunk * DIM;
        // HU = [gelu(XT@w1^T + b1) | XT@wdn^T]
        gemm_in<<<dim3(KCAT / 128, chunk / 128), 256, 0, stream>>>(Ax, Win, HU, b1);
        // densify feats in place (+aux once)
        actw_kernel<<<chunk, 256, 0, stream>>>(
            HU + HID, c * chunk, tokE, tokW, accb,
            (c == 0) ? out + (size_t)NTOK * DIM : nullptr);
        // out = HU @ Wcat^T + b2 + x
        gemm_out<<<dim3(DIM / 128, chunk / 128), 256, 0, stream>>>(
            HU, Wcat, out, b2, x, c * chunk);
    }
}